// Round 10
// baseline (367.697 us; speedup 1.0000x reference)
//
#include <hip/hip_runtime.h>
#include <math.h>

#define N_NODES 20000
#define N_EDGES 400000
#define BATCH   4096

// ---- xl = x@Wl (+ xr = x@Wr if DUAL). x: [N][K], W: [K][128], out: [N][128].
// 256 threads = 32 col-groups (4 cols, float4) x 8 node-groups (2 nodes).
// Each thread: 2 nodes x 4 cols x {l,r} = 16 accumulators. Per 4-k chunk:
// 2 LDS reads + 8 W loads -> 128 FMAs (1 LDS instr : 64 FMA; round-9 was 1:8,
// which made the LDS issue pipe the ~25us floor).
template<int K, bool DUAL>
__global__ __launch_bounds__(256)
void transform_kernel(const float* __restrict__ x,
                      const float* __restrict__ Wl,
                      const float* __restrict__ Wr,
                      float* __restrict__ xl,
                      float* __restrict__ xr)
{
    __shared__ float xs[16 * K];
    const int t  = threadIdx.x;
    const int c0 = (t & 31) * 4;         // column base (0..124)
    const int hs = t >> 5;               // node pair index (0..7)
    const int n0 = blockIdx.x * 16;

    // cooperative stage of the 16-node x tile (coalesced float4)
    {
        const float4* __restrict__ src = (const float4*)(x + (size_t)n0 * K);
        float4* dst = (float4*)xs;
        const int tot = 16 * K / 4;
#pragma unroll
        for (int i = 0; i < (tot + 255) / 256; ++i) {
            const int idx = t + i * 256;
            if (idx < tot) dst[idx] = src[idx];
        }
    }
    __syncthreads();

    float4 accl[2], accr[2];
    accl[0] = make_float4(0.f, 0.f, 0.f, 0.f); accl[1] = accl[0];
    accr[0] = accl[0];                         accr[1] = accl[0];

    float4 xA[2], xB[2];
    float4 wlA[4], wlB[4], wrA[4], wrB[4];

    auto loadX = [&](float4* xv, int k) {
        xv[0] = *(const float4*)(xs + (2 * hs + 0) * K + k);
        xv[1] = *(const float4*)(xs + (2 * hs + 1) * K + k);
    };
    auto loadW = [&](float4* wl, float4* wr, int k) {
#pragma unroll
        for (int u = 0; u < 4; ++u) {
            wl[u] = *(const float4*)(Wl + (size_t)(k + u) * 128 + c0);
            if constexpr (DUAL)
                wr[u] = *(const float4*)(Wr + (size_t)(k + u) * 128 + c0);
        }
    };
    auto fma4 = [](float4& a, float s, const float4& w) {
        a.x = fmaf(s, w.x, a.x); a.y = fmaf(s, w.y, a.y);
        a.z = fmaf(s, w.z, a.z); a.w = fmaf(s, w.w, a.w);
    };
    auto fmac = [&](const float4* xv, const float4* wl, const float4* wr) {
#pragma unroll
        for (int g = 0; g < 2; ++g) {
            fma4(accl[g], xv[g].x, wl[0]);
            fma4(accl[g], xv[g].y, wl[1]);
            fma4(accl[g], xv[g].z, wl[2]);
            fma4(accl[g], xv[g].w, wl[3]);
            if constexpr (DUAL) {
                fma4(accr[g], xv[g].x, wr[0]);
                fma4(accr[g], xv[g].y, wr[1]);
                fma4(accr[g], xv[g].z, wr[2]);
                fma4(accr[g], xv[g].w, wr[3]);
            }
        }
    };

    loadX(xA, 0); loadW(wlA, wrA, 0);
    for (int k0 = 0; k0 < K; k0 += 8) {
        if (k0 + 4 < K) { loadX(xB, k0 + 4); loadW(wlB, wrB, k0 + 4); }
        fmac(xA, wlA, wrA);
        if (k0 + 8 < K) { loadX(xA, k0 + 8); loadW(wlA, wrA, k0 + 8); }
        fmac(xB, wlB, wrB);
    }

#pragma unroll
    for (int g = 0; g < 2; ++g) {
        *(float4*)(xl + (size_t)(n0 + 2 * hs + g) * 128 + c0) = accl[g];
        if constexpr (DUAL)
            *(float4*)(xr + (size_t)(n0 + 2 * hs + g) * 128 + c0) = accr[g];
    }
}

// ---- layer-3 xr only for the 4096 pert rows (register-pipelined, gathered x)
template<int K, int G>
__global__ __launch_bounds__(128)
void transform_r_pert_kernel(const float* __restrict__ x,
                             const int* __restrict__ pert,
                             const float* __restrict__ W,
                             float* __restrict__ out)
{
    const int t  = threadIdx.x;
    const int i0 = blockIdx.x * G;

    const float* __restrict__ xrow[G];
#pragma unroll
    for (int g = 0; g < G; ++g)
        xrow[g] = x + (size_t)pert[i0 + g] * K;

    float acc[G];
#pragma unroll
    for (int g = 0; g < G; ++g) acc[g] = 0.f;

    float4 xA[G], xB[G];
    float wA[4], wB[4];

    auto loadc = [&](float4* xs, float* w, int k) {
#pragma unroll
        for (int g = 0; g < G; ++g)
            xs[g] = *(const float4*)(xrow[g] + k);
#pragma unroll
        for (int u = 0; u < 4; ++u) w[u] = W[(k + u) * 128 + t];
    };
    auto fmac = [&](const float4* xs, const float* w) {
#pragma unroll
        for (int g = 0; g < G; ++g) {
            acc[g] = fmaf(xs[g].x, w[0], acc[g]);
            acc[g] = fmaf(xs[g].y, w[1], acc[g]);
            acc[g] = fmaf(xs[g].z, w[2], acc[g]);
            acc[g] = fmaf(xs[g].w, w[3], acc[g]);
        }
    };

    loadc(xA, wA, 0);
    for (int k0 = 0; k0 < K; k0 += 8) {
        if (k0 + 4 < K) loadc(xB, wB, k0 + 4);
        fmac(xA, wA);
        if (k0 + 8 < K) loadc(xA, wA, k0 + 8);
        fmac(xB, wB);
    }

#pragma unroll
    for (int g = 0; g < G; ++g)
        out[(size_t)(i0 + g) * 128 + t] = acc[g];
}

// ---- zero an int buffer
__global__ __launch_bounds__(256)
void zero_kernel(int* __restrict__ p, int n)
{
    const int i = blockIdx.x * blockDim.x + threadIdx.x;
    if (i < n) p[i] = 0;
}

// ---- CSR build: count degrees
__global__ __launch_bounds__(256)
void count_deg_kernel(const int* __restrict__ dst, int* __restrict__ deg, int E)
{
    const int e = blockIdx.x * blockDim.x + threadIdx.x;
    if (e < E) atomicAdd(&deg[dst[e]], 1);
}

// ---- exclusive scan over 20000 degrees; one block, LDS-staged coalesced I/O.
#define CHUNK 20
#define SCAN_PAD (1024 * CHUNK)
__global__ __launch_bounds__(1024)
void scan_kernel(const int* __restrict__ deg, int* __restrict__ off,
                 int* __restrict__ cursor)
{
    __shared__ int xs[SCAN_PAD];    // 80 KB (+ pad)
    __shared__ int sums[1024];
    const int t = threadIdx.x;
    for (int i = t; i < SCAN_PAD; i += 1024)
        xs[i] = (i < N_NODES) ? deg[i] : 0;
    __syncthreads();

    const int base = t * CHUNK;
    int local[CHUNK];
    int s = 0;
#pragma unroll
    for (int i = 0; i < CHUNK; ++i) {
        local[i] = s;
        s += xs[base + i];
    }
    sums[t] = s;
    __syncthreads();
    for (int d = 1; d < 1024; d <<= 1) {
        int v = (t >= d) ? sums[t - d] : 0;
        __syncthreads();
        sums[t] += v;
        __syncthreads();
    }
    const int prev = (t == 0) ? 0 : sums[t - 1];
#pragma unroll
    for (int i = 0; i < CHUNK; ++i)
        xs[base + i] = prev + local[i];
    __syncthreads();
    for (int i = t; i < N_NODES; i += 1024) {
        const int o = xs[i];
        off[i] = o;
        cursor[i] = o;
    }
    if (t == 1023) off[N_NODES] = sums[1023];
}

// ---- scatter edges into dst-sorted order
__global__ __launch_bounds__(256)
void scatter_kernel(const int* __restrict__ src, const int* __restrict__ dst,
                    const float* __restrict__ ew, int* __restrict__ cursor,
                    int* __restrict__ ssrc, float* __restrict__ sew, int E)
{
    const int e = blockIdx.x * blockDim.x + threadIdx.x;
    if (e >= E) return;
    const int p = atomicAdd(&cursor[dst[e]], 1);
    ssrc[p] = src[e];
    sew[p]  = ew[e];
}

// ---- fused GATv2 layer: one wave per dst node, 4 edge slots in parallel.
// lane = q*16 + h*8 + j : q = edge slot (4), h = head (2), j = dim chunk (8 dims).
// LAST: edges/off indexed by nodemap[widx]; xr indexed by widx (pert-row buffer).
template<int LAST>
__global__ __launch_bounds__(256)
void gat_node_kernel(const float* __restrict__ xl, const float* __restrict__ xr,
                     const int* __restrict__ off, const int* __restrict__ ssrc,
                     const float* __restrict__ sew, const float* __restrict__ a,
                     const float* __restrict__ b, float* __restrict__ xout,
                     const int* __restrict__ nodemap, int nnodes)
{
    const int widx = (int)((blockIdx.x * blockDim.x + threadIdx.x) >> 6);
    if (widx >= nnodes) return;
    const int node = LAST ? nodemap[widx] : widx;
    const int xrrow = widx;          // == node for !LAST; batch row for LAST
    const int lane = threadIdx.x & 63;
    const int q  = lane >> 4;
    const int h  = (lane >> 3) & 1;
    const int j  = lane & 7;
    const int cb = h * 64 + j * 8;   // column base in [0,128)

    const float4 xrA = *(const float4*)(xr + (size_t)xrrow * 128 + cb);
    const float4 xrB = *(const float4*)(xr + (size_t)xrrow * 128 + cb + 4);
    const float4 aA  = *(const float4*)(a + cb);
    const float4 aB  = *(const float4*)(a + cb + 4);

    const int e0 = off[node], e1 = off[node + 1];

    float m = -1e30f, s = 0.f;
    float acc[8];
#pragma unroll
    for (int k = 0; k < 8; ++k) acc[k] = 0.f;

    for (int ebase = e0; ebase < e1; ebase += 4) {
        const int  ei    = ebase + q;
        const bool valid = ei < e1;
        const int  eic   = valid ? ei : (e1 - 1);
        const int  sn    = ssrc[eic];
        const float w    = valid ? sew[eic] : 0.f;
        const float4 xA = *(const float4*)(xl + (size_t)sn * 128 + cb);
        const float4 xB = *(const float4*)(xl + (size_t)sn * 128 + cb + 4);

        float v0 = xA.x + xrA.x, v1 = xA.y + xrA.y;
        float v2 = xA.z + xrA.z, v3 = xA.w + xrA.w;
        float v4 = xB.x + xrB.x, v5 = xB.y + xrB.y;
        float v6 = xB.z + xrB.z, v7 = xB.w + xrB.w;
        v0 = fmaxf(v0, 0.2f * v0); v1 = fmaxf(v1, 0.2f * v1);
        v2 = fmaxf(v2, 0.2f * v2); v3 = fmaxf(v3, 0.2f * v3);
        v4 = fmaxf(v4, 0.2f * v4); v5 = fmaxf(v5, 0.2f * v5);
        v6 = fmaxf(v6, 0.2f * v6); v7 = fmaxf(v7, 0.2f * v7);
        float t0 = fmaf(v0, aA.x, v1 * aA.y);
        float t1 = fmaf(v2, aA.z, v3 * aA.w);
        float t2 = fmaf(v4, aB.x, v5 * aB.y);
        float t3 = fmaf(v6, aB.z, v7 * aB.w);
        float p = (t0 + t1) + (t2 + t3);
        p += __shfl_xor(p, 1, 64);
        p += __shfl_xor(p, 2, 64);
        p += __shfl_xor(p, 4, 64);
        p = valid ? p : -1e30f;

        // online softmax (one native exp per round per lane)
        const float d   = p - m;
        const float t   = __expf(-fabsf(d));
        const bool  pos = d > 0.f;
        const float r   = pos ? t : 1.f;
        const float ex  = pos ? 1.f : t;
        m = pos ? p : m;
        const float c = ex * w;
        s = s * r + ex;
        acc[0] = acc[0] * r + c * xA.x;
        acc[1] = acc[1] * r + c * xA.y;
        acc[2] = acc[2] * r + c * xA.z;
        acc[3] = acc[3] * r + c * xA.w;
        acc[4] = acc[4] * r + c * xB.x;
        acc[5] = acc[5] * r + c * xB.y;
        acc[6] = acc[6] * r + c * xB.z;
        acc[7] = acc[7] * r + c * xB.w;
    }

    // ---- merge the 4 slot states (across q: lane strides 16, 32)
    float mg = fmaxf(m, __shfl_xor(m, 16, 64));
    mg = fmaxf(mg, __shfl_xor(mg, 32, 64));
    const float rq = __expf(m - mg);        // 0 for dead slots
    float sq = s * rq;
    sq += __shfl_xor(sq, 16, 64);
    sq += __shfl_xor(sq, 32, 64);
#pragma unroll
    for (int k = 0; k < 8; ++k) {
        float v = acc[k] * rq;
        v += __shfl_xor(v, 16, 64);
        v += __shfl_xor(v, 32, 64);
        acc[k] = v;
    }
    const float inv = 1.f / (sq + 1e-16f);

    if (!LAST) {
        if (q == 0) {
            float o[8];
#pragma unroll
            for (int k = 0; k < 8; ++k) {
                float u = acc[k] * inv + b[cb + k];
                o[k] = u > 0.f ? u : expm1f(u);
            }
            *(float4*)(xout + (size_t)node * 128 + cb)     = make_float4(o[0], o[1], o[2], o[3]);
            *(float4*)(xout + (size_t)node * 128 + cb + 4) = make_float4(o[4], o[5], o[6], o[7]);
        }
    } else {
        float o[8];
#pragma unroll
        for (int k = 0; k < 8; ++k) {
            const float v = acc[k] * inv;
            o[k] = 0.5f * (v + __shfl_xor(v, 8, 64)) + b[j * 8 + k];
        }
        if (q == 0 && h == 0) {
            *(float4*)(xout + (size_t)widx * 64 + j * 8)     = make_float4(o[0], o[1], o[2], o[3]);
            *(float4*)(xout + (size_t)widx * 64 + j * 8 + 4) = make_float4(o[4], o[5], o[6], o[7]);
        }
    }
}

extern "C" void kernel_launch(void* const* d_in, const int* in_sizes, int n_in,
                              void* d_out, int out_size, void* d_ws, size_t ws_size,
                              hipStream_t stream)
{
    const int*   pert = (const int*)d_in[0];
    const int*   eidx = (const int*)d_in[1];
    const float* ew   = (const float*)d_in[2];
    const float* emb  = (const float*)d_in[3];
    const float* Wl[4] = {(const float*)d_in[4],  (const float*)d_in[8],
                          (const float*)d_in[12], (const float*)d_in[16]};
    const float* Wr[4] = {(const float*)d_in[5],  (const float*)d_in[9],
                          (const float*)d_in[13], (const float*)d_in[17]};
    const float* av[4] = {(const float*)d_in[6],  (const float*)d_in[10],
                          (const float*)d_in[14], (const float*)d_in[18]};
    const float* bv[4] = {(const float*)d_in[7],  (const float*)d_in[11],
                          (const float*)d_in[15], (const float*)d_in[19]};

    const int N = N_NODES, E = N_EDGES;
    const int* srcp = eidx;
    const int* dstp = eidx + E;

    // workspace layout
    float* ws   = (float*)d_ws;
    float* xbuf = ws;                              // N*128 f
    float* xl   = xbuf + (size_t)N * 128;          // N*128 f
    float* xr   = xl   + (size_t)N * 128;          // N*128 f (layer3: 4096 pert rows)
    int*   deg  = (int*)(xr + (size_t)N * 128);    // N     i
    int*   off  = deg + N;                         // N+1   i
    int*   cur  = off + N + 1;                     // N     i
    int*   ssrc = cur + N;                         // E     i
    float* sew  = (float*)(ssrc + E);              // E     f

    // ---- build dst-sorted CSR once (graph static across layers)
    zero_kernel<<<(N + 255) / 256, 256, 0, stream>>>(deg, N);
    count_deg_kernel<<<(E + 255) / 256, 256, 0, stream>>>(dstp, deg, E);
    scan_kernel<<<1, 1024, 0, stream>>>(deg, off, cur);
    scatter_kernel<<<(E + 255) / 256, 256, 0, stream>>>(srcp, dstp, ew, cur,
                                                        ssrc, sew, E);

    const float* x = emb;
    for (int layer = 0; layer < 3; ++layer) {
        if (layer == 0)
            transform_kernel<64, true><<<N / 16, 256, 0, stream>>>(
                x, Wl[layer], Wr[layer], xl, xr);
        else
            transform_kernel<128, true><<<N / 16, 256, 0, stream>>>(
                x, Wl[layer], Wr[layer], xl, xr);

        gat_node_kernel<0><<<(N * 64 + 255) / 256, 256, 0, stream>>>(
            xl, xr, off, ssrc, sew, av[layer], bv[layer], xbuf, nullptr, N);
        x = xbuf;
    }

    // ---- layer 3: xl for all nodes, xr only for pert rows
    transform_kernel<128, false><<<N / 16, 256, 0, stream>>>(
        x, Wl[3], nullptr, xl, nullptr);
    transform_r_pert_kernel<128, 8><<<BATCH / 8, 128, 0, stream>>>(
        x, pert, Wr[3], xr);
    gat_node_kernel<1><<<(BATCH * 64 + 255) / 256, 256, 0, stream>>>(
        xl, xr, off, ssrc, sew, av[3], bv[3], (float*)d_out, pert, BATCH);
}

// Round 11
// 277.168 us; speedup vs baseline: 1.3266x; 1.3266x over previous
//
#include <hip/hip_runtime.h>
#include <math.h>

#define N_NODES 20000
#define N_EDGES 400000
#define BATCH   4096
#define MTILES  (N_NODES / 16)   // 1250

typedef __attribute__((ext_vector_type(8))) short short8v;
typedef __attribute__((ext_vector_type(4))) float f32x4;

// ---- split fp32 into bf16 hi + bf16 lo (truncation; hi+lo ~ 16 mantissa bits)
__device__ __forceinline__ void bf16split(float v, short& h, short& l)
{
    unsigned u  = __float_as_uint(v);
    unsigned hu = u & 0xFFFF0000u;
    h = (short)(hu >> 16);
    const float lo = v - __uint_as_float(hu);
    l = (short)(__float_as_uint(lo) >> 16);
}

// ---- pack x[N][K] (fp32) into MFMA A-fragments, bf16 hi/lo.
// A-frag (16x16x32): lane&15 = M-row, k = (lane>>4)*8 + e.
// layout: xpk[((mtile*KB + kb)*2 + hl)*512 + lane*8 + e]
template<int K>
__global__ __launch_bounds__(256)
void pack_x_kernel(const float* __restrict__ x, short* __restrict__ xpk)
{
    constexpr int KB = K / 32;
    const int t = blockIdx.x * 256 + threadIdx.x;
    if (t >= MTILES * KB * 64) return;
    const int lane  = t & 63;
    const int kb    = (t >> 6) % KB;
    const int mtile = t / (64 * KB);
    const int node  = mtile * 16 + (lane & 15);
    const int k0    = kb * 32 + (lane >> 4) * 8;
    const float* xp = x + (size_t)node * K + k0;
    short8v h, l;
#pragma unroll
    for (int e = 0; e < 8; ++e) {
        short hh, ll; bf16split(xp[e], hh, ll);
        h[e] = hh; l[e] = ll;
    }
    short* ob = xpk + ((size_t)(mtile * KB + kb) * 2) * 512 + lane * 8;
    *(short8v*)ob         = h;
    *(short8v*)(ob + 512) = l;
}

// ---- pack W[K][128] x2 (Wl,Wr) into B-fragments, bf16 hi/lo.
// B-frag: lane&15 = N-col, k = (lane>>4)*8 + e. nt 0..7 = Wl, 8..15 = Wr.
template<int K>
__global__ __launch_bounds__(256)
void pack_w_kernel(const float* __restrict__ Wl, const float* __restrict__ Wr,
                   short* __restrict__ wpk)
{
    constexpr int KB = K / 32;
    const int t = blockIdx.x * 256 + threadIdx.x;
    if (t >= 16 * KB * 64) return;
    const int lane = t & 63;
    const int kb   = (t >> 6) % KB;
    const int nt   = t / (64 * KB);
    const float* W = (nt < 8) ? Wl : Wr;
    const int col  = (nt & 7) * 16 + (lane & 15);
    const int k0   = kb * 32 + (lane >> 4) * 8;
    short8v h, l;
#pragma unroll
    for (int e = 0; e < 8; ++e) {
        short hh, ll; bf16split(W[(size_t)(k0 + e) * 128 + col], hh, ll);
        h[e] = hh; l[e] = ll;
    }
    short* ob = wpk + ((size_t)(nt * KB + kb) * 2) * 512 + lane * 8;
    *(short8v*)ob         = h;
    *(short8v*)(ob + 512) = l;
}

// ---- MFMA transform: D = x@W for 16 (or 8) column-tiles of [Wl|Wr].
// bf16x3 compensation: acc = AhBh + AhBl + AlBh (shared fp32 accumulator).
// D layout (m89-verified): col = lane&15, row = (lane>>4)*4 + reg.
template<int KB, int NWAVES>
__global__ __launch_bounds__(NWAVES * 64)
void mfma_transform_kernel(const short* __restrict__ xpk,
                           const short* __restrict__ wpk,
                           float* __restrict__ xl, float* __restrict__ xr)
{
    const int mtile = blockIdx.x;
    const int wid   = threadIdx.x >> 6;
    const int lane  = threadIdx.x & 63;

    short8v ah[KB], al[KB];
    const short* ab = xpk + ((size_t)mtile * KB * 2) * 512 + lane * 8;
#pragma unroll
    for (int kb = 0; kb < KB; ++kb) {
        ah[kb] = *(const short8v*)(ab + (size_t)(kb * 2 + 0) * 512);
        al[kb] = *(const short8v*)(ab + (size_t)(kb * 2 + 1) * 512);
    }

#pragma unroll
    for (int i = 0; i < 4; ++i) {
        const int nt = wid * 4 + i;
        const short* bb = wpk + ((size_t)nt * KB * 2) * 512 + lane * 8;
        f32x4 acc = {0.f, 0.f, 0.f, 0.f};
#pragma unroll
        for (int kb = 0; kb < KB; ++kb) {
            const short8v bh = *(const short8v*)(bb + (size_t)(kb * 2 + 0) * 512);
            const short8v bl = *(const short8v*)(bb + (size_t)(kb * 2 + 1) * 512);
            acc = __builtin_amdgcn_mfma_f32_16x16x32_bf16(ah[kb], bh, acc, 0, 0, 0);
            acc = __builtin_amdgcn_mfma_f32_16x16x32_bf16(ah[kb], bl, acc, 0, 0, 0);
            acc = __builtin_amdgcn_mfma_f32_16x16x32_bf16(al[kb], bh, acc, 0, 0, 0);
        }
        float* out = (nt < 8) ? xl : xr;
        const int colb = (nt & 7) * 16 + (lane & 15);
        const int row0 = mtile * 16 + (lane >> 4) * 4;
#pragma unroll
        for (int r = 0; r < 4; ++r)
            out[(size_t)(row0 + r) * 128 + colb] = acc[r];
    }
}

// ---- layer-3 xr only for the 4096 pert rows (scalar, register-pipelined)
template<int K, int G>
__global__ __launch_bounds__(128)
void transform_r_pert_kernel(const float* __restrict__ x,
                             const int* __restrict__ pert,
                             const float* __restrict__ W,
                             float* __restrict__ out)
{
    const int t  = threadIdx.x;
    const int i0 = blockIdx.x * G;

    const float* __restrict__ xrow[G];
#pragma unroll
    for (int g = 0; g < G; ++g)
        xrow[g] = x + (size_t)pert[i0 + g] * K;

    float acc[G];
#pragma unroll
    for (int g = 0; g < G; ++g) acc[g] = 0.f;

    float4 xA[G], xB[G];
    float wA[4], wB[4];

    auto loadc = [&](float4* xs, float* w, int k) {
#pragma unroll
        for (int g = 0; g < G; ++g)
            xs[g] = *(const float4*)(xrow[g] + k);
#pragma unroll
        for (int u = 0; u < 4; ++u) w[u] = W[(k + u) * 128 + t];
    };
    auto fmac = [&](const float4* xs, const float* w) {
#pragma unroll
        for (int g = 0; g < G; ++g) {
            acc[g] = fmaf(xs[g].x, w[0], acc[g]);
            acc[g] = fmaf(xs[g].y, w[1], acc[g]);
            acc[g] = fmaf(xs[g].z, w[2], acc[g]);
            acc[g] = fmaf(xs[g].w, w[3], acc[g]);
        }
    };

    loadc(xA, wA, 0);
    for (int k0 = 0; k0 < K; k0 += 8) {
        if (k0 + 4 < K) loadc(xB, wB, k0 + 4);
        fmac(xA, wA);
        if (k0 + 8 < K) loadc(xA, wA, k0 + 8);
        fmac(xB, wB);
    }

#pragma unroll
    for (int g = 0; g < G; ++g)
        out[(size_t)(i0 + g) * 128 + t] = acc[g];
}

// ---- zero an int buffer
__global__ __launch_bounds__(256)
void zero_kernel(int* __restrict__ p, int n)
{
    const int i = blockIdx.x * blockDim.x + threadIdx.x;
    if (i < n) p[i] = 0;
}

// ---- CSR build: count degrees
__global__ __launch_bounds__(256)
void count_deg_kernel(const int* __restrict__ dst, int* __restrict__ deg, int E)
{
    const int e = blockIdx.x * blockDim.x + threadIdx.x;
    if (e < E) atomicAdd(&deg[dst[e]], 1);
}

// ---- exclusive scan over 20000 degrees; one block, LDS-staged coalesced I/O.
#define CHUNK 20
#define SCAN_PAD (1024 * CHUNK)
__global__ __launch_bounds__(1024)
void scan_kernel(const int* __restrict__ deg, int* __restrict__ off,
                 int* __restrict__ cursor)
{
    __shared__ int xs[SCAN_PAD];
    __shared__ int sums[1024];
    const int t = threadIdx.x;
    for (int i = t; i < SCAN_PAD; i += 1024)
        xs[i] = (i < N_NODES) ? deg[i] : 0;
    __syncthreads();

    const int base = t * CHUNK;
    int local[CHUNK];
    int s = 0;
#pragma unroll
    for (int i = 0; i < CHUNK; ++i) {
        local[i] = s;
        s += xs[base + i];
    }
    sums[t] = s;
    __syncthreads();
    for (int d = 1; d < 1024; d <<= 1) {
        int v = (t >= d) ? sums[t - d] : 0;
        __syncthreads();
        sums[t] += v;
        __syncthreads();
    }
    const int prev = (t == 0) ? 0 : sums[t - 1];
#pragma unroll
    for (int i = 0; i < CHUNK; ++i)
        xs[base + i] = prev + local[i];
    __syncthreads();
    for (int i = t; i < N_NODES; i += 1024) {
        const int o = xs[i];
        off[i] = o;
        cursor[i] = o;
    }
    if (t == 1023) off[N_NODES] = sums[1023];
}

// ---- scatter edges into dst-sorted order
__global__ __launch_bounds__(256)
void scatter_kernel(const int* __restrict__ src, const int* __restrict__ dst,
                    const float* __restrict__ ew, int* __restrict__ cursor,
                    int* __restrict__ ssrc, float* __restrict__ sew, int E)
{
    const int e = blockIdx.x * blockDim.x + threadIdx.x;
    if (e >= E) return;
    const int p = atomicAdd(&cursor[dst[e]], 1);
    ssrc[p] = src[e];
    sew[p]  = ew[e];
}

// ---- fused GATv2 layer: one wave per dst node, 4 edge slots in parallel.
template<int LAST>
__global__ __launch_bounds__(256)
void gat_node_kernel(const float* __restrict__ xl, const float* __restrict__ xr,
                     const int* __restrict__ off, const int* __restrict__ ssrc,
                     const float* __restrict__ sew, const float* __restrict__ a,
                     const float* __restrict__ b, float* __restrict__ xout,
                     const int* __restrict__ nodemap, int nnodes)
{
    const int widx = (int)((blockIdx.x * blockDim.x + threadIdx.x) >> 6);
    if (widx >= nnodes) return;
    const int node = LAST ? nodemap[widx] : widx;
    const int xrrow = widx;          // == node for !LAST; batch row for LAST
    const int lane = threadIdx.x & 63;
    const int q  = lane >> 4;
    const int h  = (lane >> 3) & 1;
    const int j  = lane & 7;
    const int cb = h * 64 + j * 8;

    const float4 xrA = *(const float4*)(xr + (size_t)xrrow * 128 + cb);
    const float4 xrB = *(const float4*)(xr + (size_t)xrrow * 128 + cb + 4);
    const float4 aA  = *(const float4*)(a + cb);
    const float4 aB  = *(const float4*)(a + cb + 4);

    const int e0 = off[node], e1 = off[node + 1];

    float m = -1e30f, s = 0.f;
    float acc[8];
#pragma unroll
    for (int k = 0; k < 8; ++k) acc[k] = 0.f;

    for (int ebase = e0; ebase < e1; ebase += 4) {
        const int  ei    = ebase + q;
        const bool valid = ei < e1;
        const int  eic   = valid ? ei : (e1 - 1);
        const int  sn    = ssrc[eic];
        const float w    = valid ? sew[eic] : 0.f;
        const float4 xA = *(const float4*)(xl + (size_t)sn * 128 + cb);
        const float4 xB = *(const float4*)(xl + (size_t)sn * 128 + cb + 4);

        float v0 = xA.x + xrA.x, v1 = xA.y + xrA.y;
        float v2 = xA.z + xrA.z, v3 = xA.w + xrA.w;
        float v4 = xB.x + xrB.x, v5 = xB.y + xrB.y;
        float v6 = xB.z + xrB.z, v7 = xB.w + xrB.w;
        v0 = fmaxf(v0, 0.2f * v0); v1 = fmaxf(v1, 0.2f * v1);
        v2 = fmaxf(v2, 0.2f * v2); v3 = fmaxf(v3, 0.2f * v3);
        v4 = fmaxf(v4, 0.2f * v4); v5 = fmaxf(v5, 0.2f * v5);
        v6 = fmaxf(v6, 0.2f * v6); v7 = fmaxf(v7, 0.2f * v7);
        float t0 = fmaf(v0, aA.x, v1 * aA.y);
        float t1 = fmaf(v2, aA.z, v3 * aA.w);
        float t2 = fmaf(v4, aB.x, v5 * aB.y);
        float t3 = fmaf(v6, aB.z, v7 * aB.w);
        float p = (t0 + t1) + (t2 + t3);
        p += __shfl_xor(p, 1, 64);
        p += __shfl_xor(p, 2, 64);
        p += __shfl_xor(p, 4, 64);
        p = valid ? p : -1e30f;

        const float d   = p - m;
        const float t   = __expf(-fabsf(d));
        const bool  pos = d > 0.f;
        const float r   = pos ? t : 1.f;
        const float ex  = pos ? 1.f : t;
        m = pos ? p : m;
        const float c = ex * w;
        s = s * r + ex;
        acc[0] = acc[0] * r + c * xA.x;
        acc[1] = acc[1] * r + c * xA.y;
        acc[2] = acc[2] * r + c * xA.z;
        acc[3] = acc[3] * r + c * xA.w;
        acc[4] = acc[4] * r + c * xB.x;
        acc[5] = acc[5] * r + c * xB.y;
        acc[6] = acc[6] * r + c * xB.z;
        acc[7] = acc[7] * r + c * xB.w;
    }

    float mg = fmaxf(m, __shfl_xor(m, 16, 64));
    mg = fmaxf(mg, __shfl_xor(mg, 32, 64));
    const float rq = __expf(m - mg);
    float sq = s * rq;
    sq += __shfl_xor(sq, 16, 64);
    sq += __shfl_xor(sq, 32, 64);
#pragma unroll
    for (int k = 0; k < 8; ++k) {
        float v = acc[k] * rq;
        v += __shfl_xor(v, 16, 64);
        v += __shfl_xor(v, 32, 64);
        acc[k] = v;
    }
    const float inv = 1.f / (sq + 1e-16f);

    if (!LAST) {
        if (q == 0) {
            float o[8];
#pragma unroll
            for (int k = 0; k < 8; ++k) {
                float u = acc[k] * inv + b[cb + k];
                o[k] = u > 0.f ? u : expm1f(u);
            }
            *(float4*)(xout + (size_t)node * 128 + cb)     = make_float4(o[0], o[1], o[2], o[3]);
            *(float4*)(xout + (size_t)node * 128 + cb + 4) = make_float4(o[4], o[5], o[6], o[7]);
        }
    } else {
        float o[8];
#pragma unroll
        for (int k = 0; k < 8; ++k) {
            const float v = acc[k] * inv;
            o[k] = 0.5f * (v + __shfl_xor(v, 8, 64)) + b[j * 8 + k];
        }
        if (q == 0 && h == 0) {
            *(float4*)(xout + (size_t)widx * 64 + j * 8)     = make_float4(o[0], o[1], o[2], o[3]);
            *(float4*)(xout + (size_t)widx * 64 + j * 8 + 4) = make_float4(o[4], o[5], o[6], o[7]);
        }
    }
}

extern "C" void kernel_launch(void* const* d_in, const int* in_sizes, int n_in,
                              void* d_out, int out_size, void* d_ws, size_t ws_size,
                              hipStream_t stream)
{
    const int*   pert = (const int*)d_in[0];
    const int*   eidx = (const int*)d_in[1];
    const float* ew   = (const float*)d_in[2];
    const float* emb  = (const float*)d_in[3];
    const float* Wl[4] = {(const float*)d_in[4],  (const float*)d_in[8],
                          (const float*)d_in[12], (const float*)d_in[16]};
    const float* Wr[4] = {(const float*)d_in[5],  (const float*)d_in[9],
                          (const float*)d_in[13], (const float*)d_in[17]};
    const float* av[4] = {(const float*)d_in[6],  (const float*)d_in[10],
                          (const float*)d_in[14], (const float*)d_in[18]};
    const float* bv[4] = {(const float*)d_in[7],  (const float*)d_in[11],
                          (const float*)d_in[15], (const float*)d_in[19]};

    const int N = N_NODES, E = N_EDGES;
    const int* srcp = eidx;
    const int* dstp = eidx + E;

    // workspace layout (16B-aligned sections)
    float* ws   = (float*)d_ws;
    float* xbuf = ws;                               // N*128 f
    float* xl   = xbuf + (size_t)N * 128;           // N*128 f
    float* xr   = xl   + (size_t)N * 128;           // N*128 f
    short* xpk  = (short*)(xr + (size_t)N * 128);   // MTILES*4*2*512 = 5.12M shorts
    short* wpk  = xpk + (size_t)MTILES * 4 * 2 * 512; // 4 layers x 65536 shorts
    int*   deg  = (int*)(wpk + 4 * 65536);          // N
    int*   off  = deg + N;                          // N+1
    int*   cur  = off + N + 1;                      // N
    int*   ssrc = cur + N;                          // E
    float* sew  = (float*)(ssrc + E);               // E

    // ---- build dst-sorted CSR once
    zero_kernel<<<(N + 255) / 256, 256, 0, stream>>>(deg, N);
    count_deg_kernel<<<(E + 255) / 256, 256, 0, stream>>>(dstp, deg, E);
    scan_kernel<<<1, 1024, 0, stream>>>(deg, off, cur);
    scatter_kernel<<<(E + 255) / 256, 256, 0, stream>>>(srcp, dstp, ew, cur,
                                                        ssrc, sew, E);

    // ---- pack all W fragments (bf16 hi/lo) once
    pack_w_kernel<64><<<8,  256, 0, stream>>>(Wl[0], Wr[0], wpk);
    pack_w_kernel<128><<<16, 256, 0, stream>>>(Wl[1], Wr[1], wpk + 1 * 65536);
    pack_w_kernel<128><<<16, 256, 0, stream>>>(Wl[2], Wr[2], wpk + 2 * 65536);
    pack_w_kernel<128><<<16, 256, 0, stream>>>(Wl[3], Wr[3], wpk + 3 * 65536);

    // ---- layer 0 (K=64)
    pack_x_kernel<64><<<MTILES * 2 * 64 / 256, 256, 0, stream>>>(emb, xpk);
    mfma_transform_kernel<2, 4><<<MTILES, 256, 0, stream>>>(xpk, wpk, xl, xr);
    gat_node_kernel<0><<<(N * 64 + 255) / 256, 256, 0, stream>>>(
        xl, xr, off, ssrc, sew, av[0], bv[0], xbuf, nullptr, N);

    // ---- layers 1,2 (K=128)
    for (int layer = 1; layer < 3; ++layer) {
        pack_x_kernel<128><<<MTILES * 4 * 64 / 256, 256, 0, stream>>>(xbuf, xpk);
        mfma_transform_kernel<4, 4><<<MTILES, 256, 0, stream>>>(
            xpk, wpk + layer * 65536, xl, xr);
        gat_node_kernel<0><<<(N * 64 + 255) / 256, 256, 0, stream>>>(
            xl, xr, off, ssrc, sew, av[layer], bv[layer], xbuf, nullptr, N);
    }

    // ---- layer 3: xl for all nodes (MFMA, 8 l-tiles); xr only for pert rows
    pack_x_kernel<128><<<MTILES * 4 * 64 / 256, 256, 0, stream>>>(xbuf, xpk);
    mfma_transform_kernel<4, 2><<<MTILES, 128, 0, stream>>>(
        xpk, wpk + 3 * 65536, xl, xr);
    transform_r_pert_kernel<128, 8><<<BATCH / 8, 128, 0, stream>>>(
        xbuf, pert, Wr[3], xr);
    gat_node_kernel<1><<<(BATCH * 64 + 255) / 256, 256, 0, stream>>>(
        xl, xr, off, ssrc, sew, av[3], bv[3], (float*)d_out, pert, BATCH);
}